// Round 4
// baseline (219.502 us; speedup 1.0000x reference)
//
#include <hip/hip_runtime.h>
#include <cstddef>

#define HDIM 2048
#define NE 64
#define TOPK 4
#define NTHREADS 256
#define KC 32            // k-chunk staged per LDS buffer
#define BM2 32           // finisher tokens per block

// ---------- transpose+scale pre-pass: wt[k][e] = w[e][k] * scale[k] ----------
__global__ __launch_bounds__(256) void transpose_w_kernel(
    const float* __restrict__ w, const float* __restrict__ scale,
    float* __restrict__ wt)
{
    __shared__ float Wl[64][65];
    const int tid = threadIdx.x;
    const int k0 = blockIdx.x * 64;          // grid = HDIM/64 = 32
    #pragma unroll
    for (int q = 0; q < 4; q++) {
        int f = tid + 256 * q;               // 0..1023
        int e = f >> 4;
        int k4 = (f & 15) * 4;
        float4 v = *(const float4*)(w + (size_t)e * HDIM + k0 + k4);
        Wl[e][k4 + 0] = v.x; Wl[e][k4 + 1] = v.y;
        Wl[e][k4 + 2] = v.z; Wl[e][k4 + 3] = v.w;
    }
    __syncthreads();
    #pragma unroll
    for (int q = 0; q < 4; q++) {
        int f = tid + 256 * q;
        int k = f >> 4;
        int e4 = (f & 15) * 4;
        float s = scale[k0 + k];
        float4 v;
        v.x = Wl[e4 + 0][k] * s; v.y = Wl[e4 + 1][k] * s;
        v.z = Wl[e4 + 2][k] * s; v.w = Wl[e4 + 3][k] * s;
        *(float4*)(wt + (size_t)(k0 + k) * NE + e4) = v;
    }
}

// ---------- GEMM: coalesced LDS-staged A (stride-33, conflict-free), B in SGPRs ----------
template<int KS>
__global__ __launch_bounds__(NTHREADS) void gemm_kernel(
    const float* __restrict__ x, const float* __restrict__ wt,
    float* __restrict__ sp0,     // partial scores, ks=0 (probs region)
    float* __restrict__ spws,    // partial scores, ks=1..KS-1 (ws), stride tokens*NE
    float* __restrict__ sq,      // [KS][tokens] partial ssq
    int tokens)
{
    constexpr int KR = HDIM / KS;    // k-range per block
    constexpr int NCH = KR / KC;     // chunks
    __shared__ float As[2][64][33];  // stride 33: column read bank = (t+k)%32, 2/bank = free

    const int tid = threadIdx.x;
    const int lane = tid & 63;                                    // token within tile
    const int eg = __builtin_amdgcn_readfirstlane(tid >> 6);      // expert group (uniform)
    const int ks = blockIdx.x & (KS - 1);
    const int tok0 = (blockIdx.x / KS) * 64;
    const int k0 = ks * KR;

    // staging map: thread -> (token st, 8-float k-segment sk); 16B-coalesced per 16 lanes
    const int st = tid >> 2;
    const int sk = (tid & 3) * 8;
    const float4* srow = (const float4*)(x + (size_t)(tok0 + st) * HDIM + k0 + sk);
    const float* bb = wt + (size_t)k0 * NE + eg * 16;             // uniform -> s_load

    float acc[16];
    #pragma unroll
    for (int e = 0; e < 16; e++) acc[e] = 0.f;
    float ssq = 0.f;                 // per-thread over its staged elements

    float4 p0 = srow[0], p1 = srow[1];
    {   // write chunk 0
        float t0[8];
        *(float4*)t0 = p0; *(float4*)(t0 + 4) = p1;
        #pragma unroll
        for (int j = 0; j < 8; j++) { As[0][st][sk + j] = t0[j]; ssq = fmaf(t0[j], t0[j], ssq); }
    }
    __syncthreads();

    int b = 0;
    for (int c = 0; c < NCH; ++c) {
        if (c + 1 < NCH) { p0 = srow[(c + 1) * 8]; p1 = srow[(c + 1) * 8 + 1]; }  // in flight under compute
        const float* bch = bb + (size_t)c * KC * NE;
        #pragma unroll
        for (int k = 0; k < KC; k++) {
            float a = As[b][lane][k];            // ds_read_b32, conflict-free
            const float* br = bch + k * NE;      // uniform -> s_load_dwordx16
            #pragma unroll
            for (int e = 0; e < 16; e++) acc[e] = fmaf(a, br[e], acc[e]);
        }
        if (c + 1 < NCH) {
            float t0[8];
            *(float4*)t0 = p0; *(float4*)(t0 + 4) = p1;
            #pragma unroll
            for (int j = 0; j < 8; j++) { As[b ^ 1][st][sk + j] = t0[j]; ssq = fmaf(t0[j], t0[j], ssq); }
        }
        __syncthreads();             // one barrier/chunk: ends reads of [b], publishes [b^1]
        b ^= 1;
    }

    // ssq: 4 staging threads per token are adjacent lanes (tid = st*4 + q)
    ssq += __shfl_xor(ssq, 1, 64);
    ssq += __shfl_xor(ssq, 2, 64);
    if ((tid & 3) == 0) sq[(size_t)ks * tokens + tok0 + st] = ssq;

    float* sp = (ks == 0) ? sp0 : (spws + (size_t)(ks - 1) * tokens * NE);
    float* dst = sp + (size_t)(tok0 + lane) * NE + eg * 16;
    #pragma unroll
    for (int q = 0; q < 4; q++) {
        float4 v;
        v.x = acc[4*q + 0]; v.y = acc[4*q + 1];
        v.z = acc[4*q + 2]; v.w = acc[4*q + 3];
        *(float4*)(dst + 4*q) = v;
    }
}

// ---------- finisher: sum KS partials, rmsnorm factor, softmax, top-4 ----------
template<int KS>
__global__ __launch_bounds__(NTHREADS) void finish_kernel(
    const float* __restrict__ sp0, const float* __restrict__ spws,
    const float* __restrict__ sq, const float* __restrict__ pes,
    float* __restrict__ probs, float* __restrict__ tkw, float* __restrict__ tki,
    int tokens)
{
    __shared__ float Sl[BM2 * 65];
    __shared__ float Pl[BM2 * 65];
    __shared__ float FN[BM2];
    __shared__ float RS[BM2];

    const int tid = threadIdx.x;
    const int tok0 = blockIdx.x * BM2;       // grid = tokens/32

    if (tid < BM2) {
        float ss = 0.f;
        #pragma unroll
        for (int i = 0; i < KS; i++) ss += sq[(size_t)i * tokens + tok0 + tid];
        FN[tid] = rsqrtf(ss * (1.0f / HDIM) + 1e-6f) * 0.022097086912079612f; // * H^-0.5
    }
    __syncthreads();

    #pragma unroll
    for (int q = 0; q < (BM2 * 16) / NTHREADS; q++) {   // 2 float4 per thread
        int f = tid + NTHREADS * q;
        int m = f >> 4;
        int e4 = f & 15;
        float4 a = ((const float4*)sp0)[(size_t)(tok0 + m) * (NE/4) + e4];
        #pragma unroll
        for (int i = 1; i < KS; i++) {
            float4 bv = ((const float4*)(spws + (size_t)(i - 1) * tokens * NE))
                            [(size_t)(tok0 + m) * (NE/4) + e4];
            a.x += bv.x; a.y += bv.y; a.z += bv.z; a.w += bv.w;
        }
        float fn = FN[m];
        int base = m * 65 + e4 * 4;
        Sl[base + 0] = a.x * fn; Sl[base + 1] = a.y * fn;
        Sl[base + 2] = a.z * fn; Sl[base + 3] = a.w * fn;
    }
    __syncthreads();

    if (tid < BM2) {
        const int m = tid;
        float mx = -3.0e38f;
        for (int e = 0; e < NE; e++) mx = fmaxf(mx, Sl[m * 65 + e]);
        float sum = 0.f;
        for (int e = 0; e < NE; e++) {
            float p = __expf(Sl[m * 65 + e] - mx);
            Pl[m * 65 + e] = p;
            sum += p;
        }
        RS[m] = 1.0f / sum;
    }
    __syncthreads();

    #pragma unroll
    for (int q = 0; q < (BM2 * 16) / NTHREADS; q++) {   // coalesced probs write
        int f = tid + NTHREADS * q;
        int m = f >> 4;
        int e0 = (f & 15) * 4;
        float rs = RS[m];
        float4 pv;
        pv.x = Pl[m * 65 + e0 + 0] * rs;
        pv.y = Pl[m * 65 + e0 + 1] * rs;
        pv.z = Pl[m * 65 + e0 + 2] * rs;
        pv.w = Pl[m * 65 + e0 + 3] * rs;
        *(float4*)&probs[(size_t)(tok0 + m) * NE + e0] = pv;
    }

    if (tid < BM2) {                 // destructive top-4, lowest-index ties
        const int m = tid;
        float wv[TOPK]; int idx[TOPK];
        float wsum = 0.f;
        #pragma unroll
        for (int kk = 0; kk < TOPK; ++kk) {
            float best = -3.0e38f; int bi = 0;
            for (int e = 0; e < NE; e++) {
                float v = Sl[m * 65 + e];
                if (v > best) { best = v; bi = e; }
            }
            Sl[m * 65 + bi] = -3.4e38f;
            float p = Pl[m * 65 + bi];
            wv[kk] = p; idx[kk] = bi; wsum += p;
        }
        float inv = 1.0f / wsum;
        size_t ob = (size_t)(tok0 + m) * TOPK;
        #pragma unroll
        for (int kk = 0; kk < TOPK; kk++) {
            tkw[ob + kk] = wv[kk] * inv * pes[idx[kk]];
            tki[ob + kk] = (float)idx[kk];   // harness reads flat buffer as float32
        }
    }
}

extern "C" void kernel_launch(void* const* d_in, const int* in_sizes, int n_in,
                              void* d_out, int out_size, void* d_ws, size_t ws_size,
                              hipStream_t stream) {
    const float* x     = (const float*)d_in[0];
    const float* w     = (const float*)d_in[1];
    const float* scale = (const float*)d_in[2];
    const float* pes   = (const float*)d_in[3];
    const int tokens = in_sizes[0] / HDIM;            // 16384

    float* probs = (float*)d_out;
    float* tkw   = probs + (size_t)tokens * NE;
    float* tki   = tkw + (size_t)tokens * TOPK;

    // ws layout: wt | spws[(KS-1) * tokens*NE] | sq[KS * tokens]
    const size_t wtN = (size_t)HDIM * NE;
    const size_t spN = (size_t)tokens * NE;
    float* wt = (float*)d_ws;

    const size_t need4 = (wtN + 3 * spN + (size_t)4 * tokens) * sizeof(float);
    const int KS = (ws_size >= need4) ? 4 : 2;

    float* spws = wt + wtN;
    float* sq   = spws + (size_t)(KS - 1) * spN;
    float* sp0  = probs;                              // overwritten by finisher

    transpose_w_kernel<<<HDIM / 64, 256, 0, stream>>>(w, scale, wt);

    const int grid1 = (tokens / 64) * KS;
    if (KS == 4)
        gemm_kernel<4><<<grid1, NTHREADS, 0, stream>>>(x, wt, sp0, spws, sq, tokens);
    else
        gemm_kernel<2><<<grid1, NTHREADS, 0, stream>>>(x, wt, sp0, spws, sq, tokens);

    const int grid2 = tokens / BM2;
    if (KS == 4)
        finish_kernel<4><<<grid2, NTHREADS, 0, stream>>>(sp0, spws, sq, pes, probs, tkw, tki, tokens);
    else
        finish_kernel<2><<<grid2, NTHREADS, 0, stream>>>(sp0, spws, sq, pes, probs, tkw, tki, tokens);
}